// Round 1
// baseline (1162.528 us; speedup 1.0000x reference)
//
#include <hip/hip_runtime.h>

#define N_USERS  200000
#define N_ITEMS  100000
#define DIM      64
#define N_NODES  300000
#define N_EDGES  1200000

// ---------------------------------------------------------------------------
// degree count (int atomics over row indices)
__global__ void deg_kernel(const int* __restrict__ row, int* __restrict__ deg) {
    int e = blockIdx.x * blockDim.x + threadIdx.x;
    if (e < N_EDGES) atomicAdd(&deg[row[e]], 1);
}

// deg -> deg_inv_sqrt (0 if deg==0)
__global__ void dis_kernel(const int* __restrict__ deg, float* __restrict__ dis) {
    int i = blockIdx.x * blockDim.x + threadIdx.x;
    if (i < N_NODES) {
        int d = deg[i];
        dis[i] = (d > 0) ? rsqrtf((float)d) : 0.0f;
    }
}

// per-edge norm = dis[row]*dis[col]
__global__ void norm_kernel(const int* __restrict__ row, const int* __restrict__ col,
                            const float* __restrict__ dis, float* __restrict__ nrm) {
    int e = blockIdx.x * blockDim.x + threadIdx.x;
    if (e < N_EDGES) nrm[e] = dis[row[e]] * dis[col[e]];
}

// h_cur = concat(user_emb, item_emb); acc (d_out) = same
__global__ void init_kernel(const float* __restrict__ ue, const float* __restrict__ ie,
                            float* __restrict__ h, float* __restrict__ acc) {
    const int total = N_NODES * DIM / 4;          // float4 elements
    const int uend  = N_USERS * DIM / 4;
    int i = blockIdx.x * blockDim.x + threadIdx.x;
    if (i < total) {
        float4 v = (i < uend) ? ((const float4*)ue)[i]
                              : ((const float4*)ie)[i - uend];
        ((float4*)h)[i]   = v;
        ((float4*)acc)[i] = v;
    }
}

// one 64-lane wave per edge: lane d handles dim d. Coalesced gather + coalesced
// disjoint-address atomics (contention only between edges sharing a row; avg deg 4).
__global__ void scatter_kernel(const float* __restrict__ h,
                               const int* __restrict__ row,
                               const int* __restrict__ col,
                               const float* __restrict__ nrm,
                               float* __restrict__ out) {
    long long t = (long long)blockIdx.x * blockDim.x + threadIdx.x;
    int e = (int)(t >> 6);
    int d = (int)(t & 63);
    if (e >= N_EDGES) return;
    int   r = row[e];
    int   c = col[e];
    float w = nrm[e];
    float v = h[(long long)c * DIM + d] * w;
    atomicAdd(&out[(long long)r * DIM + d], v);
}

// acc += h
__global__ void add_kernel(const float* __restrict__ h, float* __restrict__ acc) {
    const int total = N_NODES * DIM / 4;
    int i = blockIdx.x * blockDim.x + threadIdx.x;
    if (i < total) {
        float4 a = ((float4*)acc)[i];
        float4 b = ((const float4*)h)[i];
        a.x += b.x; a.y += b.y; a.z += b.z; a.w += b.w;
        ((float4*)acc)[i] = a;
    }
}

// acc *= 0.25
__global__ void scale_kernel(float* __restrict__ acc) {
    const int total = N_NODES * DIM / 4;
    int i = blockIdx.x * blockDim.x + threadIdx.x;
    if (i < total) {
        float4 a = ((float4*)acc)[i];
        a.x *= 0.25f; a.y *= 0.25f; a.z *= 0.25f; a.w *= 0.25f;
        ((float4*)acc)[i] = a;
    }
}

extern "C" void kernel_launch(void* const* d_in, const int* in_sizes, int n_in,
                              void* d_out, int out_size, void* d_ws, size_t ws_size,
                              hipStream_t stream) {
    const float* ue  = (const float*)d_in[0];
    const float* ie  = (const float*)d_in[1];
    const int*   ei  = (const int*)d_in[2];
    const int*   row = ei;                 // edge_index[0]
    const int*   col = ei + N_EDGES;       // edge_index[1]
    float*       out = (float*)d_out;      // doubles as the acc buffer

    // workspace layout
    char*  ws     = (char*)d_ws;
    size_t embB   = (size_t)N_NODES * DIM * sizeof(float);      // 76.8 MB
    float* h_cur  = (float*)(ws);
    float* h_next = (float*)(ws + embB);
    float* nrm    = (float*)(ws + 2 * embB);
    float* dis    = nrm + N_EDGES;
    int*   deg    = (int*)(dis + N_NODES);

    const int B = 256;
    const int totalV4 = N_NODES * DIM / 4;

    // degree + norm
    hipMemsetAsync(deg, 0, (size_t)N_NODES * sizeof(int), stream);
    deg_kernel <<<(N_EDGES + B - 1) / B, B, 0, stream>>>(row, deg);
    dis_kernel <<<(N_NODES + B - 1) / B, B, 0, stream>>>(deg, dis);
    norm_kernel<<<(N_EDGES + B - 1) / B, B, 0, stream>>>(row, col, dis, nrm);

    // h0 = x, acc = x
    init_kernel<<<(totalV4 + B - 1) / B, B, 0, stream>>>(ue, ie, h_cur, out);

    // 3 propagation layers
    for (int l = 0; l < 3; ++l) {
        hipMemsetAsync(h_next, 0, embB, stream);
        long long threads = (long long)N_EDGES * 64;
        scatter_kernel<<<(unsigned)((threads + B - 1) / B), B, 0, stream>>>(
            h_cur, row, col, nrm, h_next);
        add_kernel<<<(totalV4 + B - 1) / B, B, 0, stream>>>(h_next, out);
        float* tmp = h_cur; h_cur = h_next; h_next = tmp;
    }

    scale_kernel<<<(totalV4 + B - 1) / B, B, 0, stream>>>(out);
}

// Round 2
// 529.848 us; speedup vs baseline: 2.1941x; 2.1941x over previous
//
#include <hip/hip_runtime.h>

#define N_USERS   200000
#define N_ITEMS   100000
#define DIM       64
#define N_NODES   300000
#define N_EDGES   1200000
#define NBLK_SCAN ((N_NODES + 255) / 256)

// ---------------------------------------------------------------------------
// degree count over row indices
__global__ void deg_kernel(const int* __restrict__ row, int* __restrict__ deg) {
    int e = blockIdx.x * blockDim.x + threadIdx.x;
    if (e < N_EDGES) atomicAdd(&deg[row[e]], 1);
}

// deg -> deg_inv_sqrt (0 if deg==0)
__global__ void dis_kernel(const int* __restrict__ deg, float* __restrict__ dis) {
    int i = blockIdx.x * blockDim.x + threadIdx.x;
    if (i < N_NODES) {
        int d = deg[i];
        dis[i] = (d > 0) ? rsqrtf((float)d) : 0.0f;
    }
}

// block-level exclusive scan of deg; emits per-block sums
__global__ void scan1_kernel(const int* __restrict__ deg, int* __restrict__ local_ex,
                             int* __restrict__ bsum) {
    __shared__ int s[256];
    int i = blockIdx.x * 256 + threadIdx.x;
    int v = (i < N_NODES) ? deg[i] : 0;
    s[threadIdx.x] = v;
    __syncthreads();
    for (int off = 1; off < 256; off <<= 1) {
        int t = (threadIdx.x >= off) ? s[threadIdx.x - off] : 0;
        __syncthreads();
        s[threadIdx.x] += t;
        __syncthreads();
    }
    if (i < N_NODES) local_ex[i] = s[threadIdx.x] - v;   // exclusive
    if (threadIdx.x == 255) bsum[blockIdx.x] = s[255];
}

// single-block exclusive scan of the 1172 block sums
__global__ void scan2_kernel(const int* __restrict__ bsum, int* __restrict__ boff) {
    __shared__ int s[256];
    __shared__ int carry;
    if (threadIdx.x == 0) carry = 0;
    __syncthreads();
    for (int base = 0; base < NBLK_SCAN; base += 256) {
        int i = base + threadIdx.x;
        int v = (i < NBLK_SCAN) ? bsum[i] : 0;
        s[threadIdx.x] = v;
        __syncthreads();
        for (int off = 1; off < 256; off <<= 1) {
            int t = (threadIdx.x >= off) ? s[threadIdx.x - off] : 0;
            __syncthreads();
            s[threadIdx.x] += t;
            __syncthreads();
        }
        if (i < NBLK_SCAN) boff[i] = carry + s[threadIdx.x] - v;
        __syncthreads();
        if (threadIdx.x == 0) carry += s[255];
        __syncthreads();
    }
}

// row_ptr = local_ex + boff[block]; also init fill cursors
__global__ void scan3_kernel(const int* __restrict__ local_ex, const int* __restrict__ boff,
                             int* __restrict__ row_ptr, int* __restrict__ nxt) {
    int i = blockIdx.x * 256 + threadIdx.x;
    if (i < N_NODES) {
        int p = local_ex[i] + boff[i >> 8];
        row_ptr[i] = p;
        nxt[i]     = p;
    }
    if (i == 0) row_ptr[N_NODES] = N_EDGES;
}

// scatter edges into CSR slots; pack (col, norm) into int2
__global__ void fill_kernel(const int* __restrict__ row, const int* __restrict__ col,
                            const float* __restrict__ dis, int* __restrict__ nxt,
                            int2* __restrict__ edge) {
    int e = blockIdx.x * blockDim.x + threadIdx.x;
    if (e < N_EDGES) {
        int r = row[e], c = col[e];
        int pos = atomicAdd(&nxt[r], 1);
        float w = dis[r] * dis[c];
        edge[pos] = make_int2(c, __float_as_int(w));
    }
}

// out = concat(user_emb, item_emb)
__global__ void init_out_kernel(const float* __restrict__ ue, const float* __restrict__ ie,
                                float* __restrict__ out) {
    const int total = N_NODES * DIM / 4;
    const int uend  = N_USERS * DIM / 4;
    int i = blockIdx.x * blockDim.x + threadIdx.x;
    if (i < total) {
        ((float4*)out)[i] = (i < uend) ? ((const float4*)ue)[i]
                                       : ((const float4*)ie)[i - uend];
    }
}

// atomic-free pull aggregation. 16 threads per node, each owns a float4 of the
// 64-dim row. CONCAT: layer 0 reads directly from the two input tables.
// FINAL: skip h_next store, fold in the 1/(L+1) scale.
template <bool CONCAT, bool FINAL>
__global__ void pull_kernel(const float* __restrict__ hu,   // h (or user_emb)
                            const float* __restrict__ hi,   // item_emb when CONCAT
                            const int* __restrict__ row_ptr,
                            const int2* __restrict__ edge,
                            float* __restrict__ h_next,
                            float* __restrict__ out) {
    int gid  = blockIdx.x * blockDim.x + threadIdx.x;
    int node = gid >> 4;
    int q    = gid & 15;
    if (node >= N_NODES) return;
    int jb = row_ptr[node];
    int je = row_ptr[node + 1];
    float4 acc = make_float4(0.f, 0.f, 0.f, 0.f);
    for (int j = jb; j < je; ++j) {
        int2  cw = edge[j];                       // same addr across the 16-lane group
        float w  = __int_as_float(cw.y);
        const float* src;
        if (CONCAT) {
            src = (cw.x < N_USERS) ? (hu + (long long)cw.x * DIM)
                                   : (hi + (long long)(cw.x - N_USERS) * DIM);
        } else {
            src = hu + (long long)cw.x * DIM;
        }
        float4 v = ((const float4*)src)[q];
        acc.x += w * v.x; acc.y += w * v.y; acc.z += w * v.z; acc.w += w * v.w;
    }
    long long oi = (long long)node * 16 + q;
    float4 o = ((float4*)out)[oi];
    o.x += acc.x; o.y += acc.y; o.z += acc.z; o.w += acc.w;
    if (FINAL) {
        o.x *= 0.25f; o.y *= 0.25f; o.z *= 0.25f; o.w *= 0.25f;
    } else {
        ((float4*)h_next)[oi] = acc;
    }
    ((float4*)out)[oi] = o;
}

extern "C" void kernel_launch(void* const* d_in, const int* in_sizes, int n_in,
                              void* d_out, int out_size, void* d_ws, size_t ws_size,
                              hipStream_t stream) {
    const float* ue  = (const float*)d_in[0];
    const float* ie  = (const float*)d_in[1];
    const int*   ei  = (const int*)d_in[2];
    const int*   row = ei;
    const int*   col = ei + N_EDGES;
    float*       out = (float*)d_out;

    // workspace layout (~171 MB)
    float* hA       = (float*)d_ws;
    float* hB       = hA + (size_t)N_NODES * DIM;
    int2*  edge     = (int2*)(hB + (size_t)N_NODES * DIM);
    int*   row_ptr  = (int*)(edge + N_EDGES);
    int*   nxt      = row_ptr + N_NODES + 1;
    int*   deg      = nxt + N_NODES;
    float* dis      = (float*)(deg + N_NODES);
    int*   local_ex = (int*)(dis + N_NODES);
    int*   bsum     = local_ex + N_NODES;
    int*   boff     = bsum + NBLK_SCAN;

    const int B  = 256;
    const int GE = (N_EDGES + B - 1) / B;
    const int GN = (N_NODES + B - 1) / B;
    const int GP = (N_NODES * 16 + B - 1) / B;
    const int GV = (N_NODES * DIM / 4 + B - 1) / B;

    // ---- CSR build (once per launch) ----
    hipMemsetAsync(deg, 0, (size_t)N_NODES * sizeof(int), stream);
    deg_kernel  <<<GE, B, 0, stream>>>(row, deg);
    dis_kernel  <<<GN, B, 0, stream>>>(deg, dis);
    scan1_kernel<<<NBLK_SCAN, B, 0, stream>>>(deg, local_ex, bsum);
    scan2_kernel<<<1, B, 0, stream>>>(bsum, boff);
    scan3_kernel<<<NBLK_SCAN, B, 0, stream>>>(local_ex, boff, row_ptr, nxt);
    fill_kernel <<<GE, B, 0, stream>>>(row, col, dis, nxt, edge);

    // ---- out = x ----
    init_out_kernel<<<GV, B, 0, stream>>>(ue, ie, out);

    // ---- 3 pull layers (atomic-free), acc fused, scale fused into last ----
    pull_kernel<true,  false><<<GP, B, 0, stream>>>(ue, ie, row_ptr, edge, hA, out);
    pull_kernel<false, false><<<GP, B, 0, stream>>>(hA, nullptr, row_ptr, edge, hB, out);
    pull_kernel<false, true ><<<GP, B, 0, stream>>>(hB, nullptr, row_ptr, edge, nullptr, out);
}

// Round 3
// 469.425 us; speedup vs baseline: 2.4765x; 1.1287x over previous
//
#include <hip/hip_runtime.h>

#define N_USERS   200000
#define N_ITEMS   100000
#define DIM       64
#define N_NODES   300000
#define N_EDGES   1200000
#define NBLK_SCAN ((N_NODES + 255) / 256)

// ---------------------------------------------------------------------------
// degree count over row indices
__global__ void deg_kernel(const int* __restrict__ row, int* __restrict__ deg) {
    int e = blockIdx.x * blockDim.x + threadIdx.x;
    if (e < N_EDGES) atomicAdd(&deg[row[e]], 1);
}

// block-level exclusive scan of deg; emits per-block sums.
// Fused: dis = rsqrt(deg) and invd = sqrt(deg) (0 if deg==0).
__global__ void scan1_kernel(const int* __restrict__ deg, int* __restrict__ local_ex,
                             int* __restrict__ bsum, float* __restrict__ dis,
                             float* __restrict__ invd) {
    __shared__ int s[256];
    int i = blockIdx.x * 256 + threadIdx.x;
    int v = (i < N_NODES) ? deg[i] : 0;
    s[threadIdx.x] = v;
    __syncthreads();
    for (int off = 1; off < 256; off <<= 1) {
        int t = (threadIdx.x >= off) ? s[threadIdx.x - off] : 0;
        __syncthreads();
        s[threadIdx.x] += t;
        __syncthreads();
    }
    if (i < N_NODES) {
        local_ex[i] = s[threadIdx.x] - v;          // exclusive
        float fd = (float)v;
        dis[i]  = (v > 0) ? rsqrtf(fd) : 0.0f;
        invd[i] = (v > 0) ? sqrtf(fd)  : 0.0f;
    }
    if (threadIdx.x == 255) bsum[blockIdx.x] = s[255];
}

// single-block exclusive scan of the block sums
__global__ void scan2_kernel(const int* __restrict__ bsum, int* __restrict__ boff) {
    __shared__ int s[256];
    __shared__ int carry;
    if (threadIdx.x == 0) carry = 0;
    __syncthreads();
    for (int base = 0; base < NBLK_SCAN; base += 256) {
        int i = base + threadIdx.x;
        int v = (i < NBLK_SCAN) ? bsum[i] : 0;
        s[threadIdx.x] = v;
        __syncthreads();
        for (int off = 1; off < 256; off <<= 1) {
            int t = (threadIdx.x >= off) ? s[threadIdx.x - off] : 0;
            __syncthreads();
            s[threadIdx.x] += t;
            __syncthreads();
        }
        if (i < NBLK_SCAN) boff[i] = carry + s[threadIdx.x] - v;
        __syncthreads();
        if (threadIdx.x == 0) carry += s[255];
        __syncthreads();
    }
}

// row_ptr = local_ex + boff[block]; also init fill cursors
__global__ void scan3_kernel(const int* __restrict__ local_ex, const int* __restrict__ boff,
                             int* __restrict__ row_ptr, int* __restrict__ nxt) {
    int i = blockIdx.x * 256 + threadIdx.x;
    if (i < N_NODES) {
        int p = local_ex[i] + boff[i >> 8];
        row_ptr[i] = p;
        nxt[i]     = p;
    }
    if (i == 0) row_ptr[N_NODES] = N_EDGES;
}

// scatter edges into CSR slots; payload = bare col index (4 B)
__global__ void fill_kernel(const int* __restrict__ row, const int* __restrict__ col,
                            int* __restrict__ nxt, int* __restrict__ col_e) {
    int e = blockIdx.x * blockDim.x + threadIdx.x;
    if (e < N_EDGES) {
        int pos = atomicAdd(&nxt[row[e]], 1);
        col_e[pos] = col[e];
    }
}

// ---------------------------------------------------------------------------
// Atomic-free pull with pre-scaled g = h*dis.
// MODE 0: gather x (concat ue/ie) with per-edge dis[c]; store g1 = dis_r^2 * acc
// MODE 1: gather g_in;                                  store g2 = dis_r^2 * acc
// MODE 2: gather g_in (=g2); epilogue fuses acc + scale:
//         out = 0.25*(x + (g1+g2)*sqrt(deg) + dis_r*acc)
template <int MODE>
__global__ void pull_kernel(const float* __restrict__ ue, const float* __restrict__ ie,
                            const float* __restrict__ g_in,
                            const int* __restrict__ row_ptr, const int* __restrict__ col_e,
                            const float* __restrict__ dis, const float* __restrict__ invd,
                            const float* __restrict__ gA, const float* __restrict__ gB,
                            float* __restrict__ dst) {
    int gid  = blockIdx.x * blockDim.x + threadIdx.x;
    int node = gid >> 4;
    int q    = gid & 15;
    if (node >= N_NODES) return;
    int jb = row_ptr[node];
    int je = row_ptr[node + 1];
    float4 acc = make_float4(0.f, 0.f, 0.f, 0.f);

    auto gather = [&](int c) -> float4 {
        if (MODE == 0) {
            const float* src = (c < N_USERS) ? (ue + c * DIM)
                                             : (ie + (c - N_USERS) * DIM);
            return ((const float4*)src)[q];
        } else {
            return ((const float4*)(g_in + c * DIM))[q];
        }
    };

    int j = jb;
    for (; j + 1 < je; j += 2) {                 // 2-way unroll for load ILP
        int c0 = col_e[j], c1 = col_e[j + 1];
        float w0 = (MODE == 0) ? dis[c0] : 1.0f;
        float w1 = (MODE == 0) ? dis[c1] : 1.0f;
        float4 v0 = gather(c0);
        float4 v1 = gather(c1);
        acc.x += w0 * v0.x + w1 * v1.x;
        acc.y += w0 * v0.y + w1 * v1.y;
        acc.z += w0 * v0.z + w1 * v1.z;
        acc.w += w0 * v0.w + w1 * v1.w;
    }
    if (j < je) {
        int c = col_e[j];
        float w = (MODE == 0) ? dis[c] : 1.0f;
        float4 v = gather(c);
        acc.x += w * v.x; acc.y += w * v.y; acc.z += w * v.z; acc.w += w * v.w;
    }

    float dr = dis[node];
    int   oi = node * 16 + q;
    if (MODE < 2) {
        float s = dr * dr;
        float4 g = make_float4(s * acc.x, s * acc.y, s * acc.z, s * acc.w);
        ((float4*)dst)[oi] = g;
    } else {
        float iv = invd[node];
        const float* xs = (node < N_USERS) ? (ue + node * DIM)
                                           : (ie + (node - N_USERS) * DIM);
        float4 x = ((const float4*)xs)[q];
        float4 a = ((const float4*)gA)[oi];
        float4 b = ((const float4*)gB)[oi];
        float4 o;
        o.x = 0.25f * (x.x + (a.x + b.x) * iv + dr * acc.x);
        o.y = 0.25f * (x.y + (a.y + b.y) * iv + dr * acc.y);
        o.z = 0.25f * (x.z + (a.z + b.z) * iv + dr * acc.z);
        o.w = 0.25f * (x.w + (a.w + b.w) * iv + dr * acc.w);
        ((float4*)dst)[oi] = o;
    }
}

extern "C" void kernel_launch(void* const* d_in, const int* in_sizes, int n_in,
                              void* d_out, int out_size, void* d_ws, size_t ws_size,
                              hipStream_t stream) {
    const float* ue  = (const float*)d_in[0];
    const float* ie  = (const float*)d_in[1];
    const int*   ei  = (const int*)d_in[2];
    const int*   row = ei;
    const int*   col = ei + N_EDGES;
    float*       out = (float*)d_out;

    // workspace layout (~161 MB)
    float* gA       = (float*)d_ws;                       // g1
    float* gB       = gA + (size_t)N_NODES * DIM;         // g2
    int*   col_e    = (int*)(gB + (size_t)N_NODES * DIM);
    int*   row_ptr  = col_e + N_EDGES;
    int*   nxt      = row_ptr + N_NODES + 1;
    int*   deg      = nxt + N_NODES;
    float* dis      = (float*)(deg + N_NODES);
    float* invd     = dis + N_NODES;
    int*   local_ex = (int*)(invd + N_NODES);
    int*   bsum     = local_ex + N_NODES;
    int*   boff     = bsum + NBLK_SCAN;

    const int B  = 256;
    const int GE = (N_EDGES + B - 1) / B;
    const int GP = (N_NODES * 16 + B - 1) / B;

    // ---- CSR build ----
    hipMemsetAsync(deg, 0, (size_t)N_NODES * sizeof(int), stream);
    deg_kernel  <<<GE, B, 0, stream>>>(row, deg);
    scan1_kernel<<<NBLK_SCAN, B, 0, stream>>>(deg, local_ex, bsum, dis, invd);
    scan2_kernel<<<1, B, 0, stream>>>(bsum, boff);
    scan3_kernel<<<NBLK_SCAN, B, 0, stream>>>(local_ex, boff, row_ptr, nxt);
    fill_kernel <<<GE, B, 0, stream>>>(row, col, nxt, col_e);

    // ---- 3 pull layers, acc deferred into the last epilogue ----
    pull_kernel<0><<<GP, B, 0, stream>>>(ue, ie, nullptr, row_ptr, col_e, dis, invd,
                                         nullptr, nullptr, gA);
    pull_kernel<1><<<GP, B, 0, stream>>>(ue, ie, gA, row_ptr, col_e, dis, invd,
                                         nullptr, nullptr, gB);
    pull_kernel<2><<<GP, B, 0, stream>>>(ue, ie, gB, row_ptr, col_e, dis, invd,
                                         gA, gB, out);
}